// Round 20
// baseline (145.063 us; speedup 1.0000x reference)
//
#include <hip/hip_runtime.h>
#include <hip/hip_bf16.h>
#include <math.h>

typedef short s8 __attribute__((ext_vector_type(8)));
typedef float f4 __attribute__((ext_vector_type(4)));

#define HEADS 16
#define DHEAD 64
#define NSEQ 2048
#define BATCH 2
#define DIM 1024
#define ROT 32
#define KVB 32
// Q scale: head_dim^-0.5 * log2(e)  (softmax done in exp2 domain, libm exp2f --
// fast v_exp variants are QUARANTINED: rounds 13/14/15/18 all failed with them)
#define QSCALE 0.18033688011112042f

static __device__ __forceinline__ unsigned short f2bf(float f) {
    union { float f; unsigned int u; } v; v.f = f;
    unsigned int u = v.u;
    unsigned int r = (u + 0x7FFFu + ((u >> 16) & 1u)) >> 16;
    return (unsigned short)r;
}

static __device__ __forceinline__ unsigned int cvt_pk_bf16(float lo, float hi) {
    unsigned int r;
    asm volatile("v_cvt_pk_bf16_f32 %0, %1, %2" : "=v"(r) : "v"(lo), "v"(hi));
    return r;
}

// async global->LDS, 16B per lane. LDS dest is wave-uniform base + lane*16 (HW).
static __device__ __forceinline__ void gload_lds16(
        const unsigned short* g, unsigned short* l) {
    __builtin_amdgcn_global_load_lds(
        (const __attribute__((address_space(1))) void*)g,
        (__attribute__((address_space(3))) void*)l,
        16, 0, 0);
}

// ---------------- fused prep + RMSNorm (independent memory-bound work, 1 dispatch)
static __device__ __forceinline__ void tr_tile(
        const float* __restrict__ in, unsigned short* __restrict__ out,
        int K, int N, int n0, int k0, int tid, float* tile /*32*33*/) {
    int tx = tid & 31, ty = tid >> 5;  // 32 x 8
    #pragma unroll
    for (int j = 0; j < 32; j += 8)
        tile[(ty + j) * 33 + tx] = in[(size_t)(k0 + ty + j) * N + n0 + tx];
    __syncthreads();
    #pragma unroll
    for (int j = 0; j < 32; j += 8)
        out[(size_t)(n0 + ty + j) * K + k0 + tx] = f2bf(tile[tx * 33 + ty + j]);
}

__global__ __launch_bounds__(256) void prep_rms_kernel(
        const float* __restrict__ x, const float* __restrict__ gamma,
        const float* __restrict__ Wq, const float* __restrict__ Wkv,
        const float* __restrict__ Wo, const float* __restrict__ freqs,
        unsigned short* __restrict__ xn, unsigned short* __restrict__ WqT,
        unsigned short* __restrict__ WkvT, unsigned short* __restrict__ WoT,
        float* __restrict__ cs) {
    __shared__ float smem[32 * 33];
    int bid = blockIdx.x, tid = threadIdx.x;
    if (bid < 4096) {
        int row = bid;
        float4 v = ((const float4*)(x + (size_t)row * DIM))[tid];
        float ss = v.x * v.x + v.y * v.y + v.z * v.z + v.w * v.w;
        #pragma unroll
        for (int m = 1; m < 64; m <<= 1) ss += __shfl_xor(ss, m, 64);
        int wave = tid >> 6;
        if ((tid & 63) == 0) smem[wave] = ss;
        __syncthreads();
        float total = smem[0] + smem[1] + smem[2] + smem[3];
        float norm = sqrtf(total * (1.0f / DIM));
        float inv = 1.0f / fmaxf(norm, 1e-8f);
        float4 g = ((const float4*)gamma)[tid];
        ushort4 o;
        o.x = f2bf(v.x * inv * g.x);
        o.y = f2bf(v.y * inv * g.y);
        o.z = f2bf(v.z * inv * g.z);
        o.w = f2bf(v.w * inv * g.w);
        ((ushort4*)(xn + (size_t)row * DIM))[tid] = o;
    } else if (bid < 5120) {
        int idx = bid - 4096;
        tr_tile(Wq, WqT, 1024, 1024, (idx & 31) * 32, (idx >> 5) * 32, tid, smem);
    } else if (bid < 7168) {
        int idx = bid - 5120;
        tr_tile(Wkv, WkvT, 1024, 2048, (idx & 63) * 32, (idx >> 6) * 32, tid, smem);
    } else if (bid < 8192) {
        int idx = bid - 7168;
        tr_tile(Wo, WoT, 1024, 1024, (idx & 31) * 32, (idx >> 5) * 32, tid, smem);
    } else {
        int i = (bid - 8192) * 256 + tid;   // 512*256 = 2048*64
        int npos = i >> 6, j = i & 63;
        int q = j >> 4;
        int fi = (q >> 1) * 16 + (j & 15);
        float f = freqs[npos * ROT + fi];
        cs[i] = (q & 1) ? sinf(f) : cosf(f);
    }
}

// ---------------- GEMM core: block 64x128, 4 waves 2x2, wave 32x64 = acc[2][4].
// K=1024, BK=32, 3-deep counted-vmcnt pipeline (T3+T4).
static __device__ __forceinline__ void gemm_core64_p3(
        const unsigned short* __restrict__ A, const unsigned short* __restrict__ BT,
        int bm0, int bn0, unsigned short* As, unsigned short* Bs, f4 acc[2][4]) {
    const int Kd = DIM;
    int tid = threadIdx.x, lane = tid & 63, w = tid >> 6;
    int wr = w >> 1, wc = w & 1;
    int r16 = lane & 15, g8 = 8 * (lane >> 4);
    int srow = lane >> 2, scol = (lane & 3) * 8;
    const unsigned short* Ag0 = A  + (size_t)(bm0 + w * 16 + srow) * Kd + scol;
    const unsigned short* Bg0 = BT + (size_t)(bn0 + (w * 2 + 0) * 16 + srow) * Kd + scol;
    const unsigned short* Bg1 = BT + (size_t)(bn0 + (w * 2 + 1) * 16 + srow) * Kd + scol;
    unsigned short* Al  = As + w * 512;
    unsigned short* Bl0 = Bs + (w * 2 + 0) * 512;
    unsigned short* Bl1 = Bs + (w * 2 + 1) * 512;
    const unsigned short* ar = As + (wr * 32 + r16) * 32 + g8;
    const unsigned short* br = Bs + (wc * 64 + r16) * 32 + g8;
    #pragma unroll
    for (int p = 0; p < 3; ++p) {
        int k0 = p * 32;
        gload_lds16(Ag0 + k0, Al + p * 2048);
        gload_lds16(Bg0 + k0, Bl0 + p * 4096);
        gload_lds16(Bg1 + k0, Bl1 + p * 4096);
    }
    asm volatile("s_waitcnt vmcnt(6)" ::: "memory");
    __builtin_amdgcn_s_barrier();
    __builtin_amdgcn_sched_barrier(0);
    #pragma unroll
    for (int t = 0; t < 32; ++t) {
        const int cb = t % 3;
        const int aoff = cb * 2048;
        const int boff = cb * 4096;
        {
            s8 a0 = *(const s8*)(ar + aoff);
            s8 a1 = *(const s8*)(ar + aoff + 512);
            s8 b0 = *(const s8*)(br + boff);
            s8 b1 = *(const s8*)(br + boff + 512);
            s8 b2 = *(const s8*)(br + boff + 1024);
            s8 b3 = *(const s8*)(br + boff + 1536);
            acc[0][0] = __builtin_amdgcn_mfma_f32_16x16x32_bf16(a0, b0, acc[0][0], 0, 0, 0);
            acc[0][1] = __builtin_amdgcn_mfma_f32_16x16x32_bf16(a0, b1, acc[0][1], 0, 0, 0);
            acc[0][2] = __builtin_amdgcn_mfma_f32_16x16x32_bf16(a0, b2, acc[0][2], 0, 0, 0);
            acc[0][3] = __builtin_amdgcn_mfma_f32_16x16x32_bf16(a0, b3, acc[0][3], 0, 0, 0);
            acc[1][0] = __builtin_amdgcn_mfma_f32_16x16x32_bf16(a1, b0, acc[1][0], 0, 0, 0);
            acc[1][1] = __builtin_amdgcn_mfma_f32_16x16x32_bf16(a1, b1, acc[1][1], 0, 0, 0);
            acc[1][2] = __builtin_amdgcn_mfma_f32_16x16x32_bf16(a1, b2, acc[1][2], 0, 0, 0);
            acc[1][3] = __builtin_amdgcn_mfma_f32_16x16x32_bf16(a1, b3, acc[1][3], 0, 0, 0);
        }
        __builtin_amdgcn_sched_barrier(0);
        __builtin_amdgcn_s_barrier();
        if (t + 3 < 32) {
            int k3 = (t + 3) * 32;
            gload_lds16(Ag0 + k3, Al + aoff);
            gload_lds16(Bg0 + k3, Bl0 + boff);
            gload_lds16(Bg1 + k3, Bl1 + boff);
        }
        if (t + 1 < 32) {
            if (t + 3 < 32)      { asm volatile("s_waitcnt vmcnt(6)" ::: "memory"); }
            else if (t + 2 < 32) { asm volatile("s_waitcnt vmcnt(3)" ::: "memory"); }
            else                 { asm volatile("s_waitcnt vmcnt(0)" ::: "memory"); }
            __builtin_amdgcn_s_barrier();
            __builtin_amdgcn_sched_barrier(0);
        }
    }
}

// ---------------- fused QKV projection. 1D grid 1536, XCD-chunked (T1).
// Epilogues stage the 64x128 output tile in LDS (reusing Bs; K-loop ends on a
// barrier), then write FULL 128B cache lines cooperatively -> no RFO fills.
__global__ __launch_bounds__(256) void gemm_qkv(
        const unsigned short* __restrict__ xn, const unsigned short* __restrict__ WqT,
        const unsigned short* __restrict__ WkvT, const float* __restrict__ cs,
        unsigned short* __restrict__ q_h, unsigned short* __restrict__ k_h,
        unsigned short* __restrict__ v_t) {
    __shared__ unsigned short As[3 * 64 * 32];
    __shared__ unsigned short Bs[3 * 128 * 32];
    f4 acc[2][4];
    #pragma unroll
    for (int m = 0; m < 2; ++m)
        #pragma unroll
        for (int n = 0; n < 4; ++n) acc[m][n] = 0.f;
    int bid = blockIdx.x;
    int xcd = bid & 7;
    int kk = bid >> 3;                 // 0..191
    int rx = xcd >> 2, ry = xcd & 3;   // region: 2 x 4
    int bx = rx * 12 + (kk % 12);      // 0..23
    int by = ry * 16 + (kk / 12);      // 0..63
    bool isq = (bx < 8);
    int bm0 = by * 64;
    int bn0 = (isq ? bx : (bx - 8)) * 128;
    gemm_core64_p3(xn, isq ? WqT : WkvT, bm0, bn0, As, Bs, acc);
    int tid = threadIdx.x;
    int lane = tid & 63, w = tid >> 6;
    int wr = w >> 1, wc = w & 1, g = lane >> 4, c0 = lane & 15;
    unsigned short* tile = Bs;          // safe: K-loop ended on a barrier
    int b_blk = bm0 >> 11;
    int nbase = bm0 & 2047;             // batch-folded sequence base
    if (isq) {
        #pragma unroll
        for (int m = 0; m < 2; ++m)
            #pragma unroll
            for (int r = 0; r < 4; ++r) {
                int rowl = wr * 32 + m * 16 + 4 * g + r;
                int npos = nbase + rowl;
                const float* csr = cs + npos * 64;
                float a0 = acc[m][0][r] * QSCALE;
                float a1 = acc[m][1][r] * QSCALE;
                float q0 = a0 * csr[c0] - a1 * csr[16 + c0];
                float q1 = a1 * csr[32 + c0] + a0 * csr[48 + c0];
                unsigned short* trow = tile + rowl * 128 + wc * 64;
                trow[c0]      = f2bf(q0);
                trow[16 + c0] = f2bf(q1);
                trow[32 + c0] = f2bf(acc[m][2][r] * QSCALE);
                trow[48 + c0] = f2bf(acc[m][3][r] * QSCALE);
            }
        __syncthreads();
        #pragma unroll
        for (int i = 0; i < 4; ++i) {
            int L = i * 256 + tid;
            int rr = L >> 4, hh = (L >> 3) & 1, ch = L & 7;
            int npos = nbase + rr;
            s8 v = *(const s8*)(tile + rr * 128 + hh * 64 + ch * 8);
            *(s8*)(q_h + ((size_t)(b_blk * HEADS + 2 * bx + hh) * NSEQ + npos) * DHEAD + ch * 8) = v;
        }
    } else if (bx < 16) {
        #pragma unroll
        for (int m = 0; m < 2; ++m)
            #pragma unroll
            for (int r = 0; r < 4; ++r) {
                int rowl = wr * 32 + m * 16 + 4 * g + r;
                int npos = nbase + rowl;
                const float* csr = cs + npos * 64;
                float a0 = acc[m][0][r], a1 = acc[m][1][r];
                float k0v = a0 * csr[c0] - a1 * csr[16 + c0];
                float k1v = a1 * csr[32 + c0] + a0 * csr[48 + c0];
                unsigned short* trow = tile + rowl * 128 + wc * 64;
                trow[c0]      = f2bf(k0v);
                trow[16 + c0] = f2bf(k1v);
                trow[32 + c0] = f2bf(acc[m][2][r]);
                trow[48 + c0] = f2bf(acc[m][3][r]);
            }
        __syncthreads();
        #pragma unroll
        for (int i = 0; i < 4; ++i) {
            int L = i * 256 + tid;
            int rr = L >> 4, hh = (L >> 3) & 1, ch = L & 7;
            int npos = nbase + rr;
            s8 v = *(const s8*)(tile + rr * 128 + hh * 64 + ch * 8);
            *(s8*)(k_h + ((size_t)(b_blk * HEADS + 2 * (bx - 8) + hh) * NSEQ + npos) * DHEAD + ch * 8) = v;
        }
    } else {
        // V: tile[col][row] with stride 72 shorts (144B: 16B-aligned, bank-spread)
        #pragma unroll
        for (int m = 0; m < 2; ++m) {
            int r0 = wr * 32 + m * 16 + 4 * g;
            #pragma unroll
            for (int n = 0; n < 4; ++n) {
                int col = wc * 64 + n * 16 + c0;
                uint2 pk;
                pk.x = cvt_pk_bf16(acc[m][n][0], acc[m][n][1]);
                pk.y = cvt_pk_bf16(acc[m][n][2], acc[m][n][3]);
                *(uint2*)(tile + col * 72 + r0) = pk;
            }
        }
        __syncthreads();
        #pragma unroll
        for (int i = 0; i < 4; ++i) {
            int L = i * 256 + tid;          // 1024 chunks: 128 cols x 8
            int col = L >> 3, ch = L & 7;
            int h = 2 * (bx - 16) + (col >> 6);
            int d = col & 63;
            s8 v = *(const s8*)(tile + col * 72 + ch * 8);
            *(s8*)(v_t + ((size_t)(b_blk * HEADS + h) * DHEAD + d) * NSEQ + nbase + ch * 8) = v;
        }
    }
}

// ---------------- causal flash attention: KVB=32 tiles, 20 KB LDS ----
// K tile [32][64] (chunk^row&7 swizzle), V tile [64][32] (chunk^row&3),
// p_lds per-wave [16][32] (chunk^row&3). Same fence idiom, libm exp2f.

static __device__ __forceinline__ void stage_kv32(
        const unsigned short* __restrict__ kb, const unsigned short* __restrict__ vb,
        int j0, unsigned short* Kd, unsigned short* Vd, int w, int lane) {
    // K: wave w stages rows w*8..w*8+7 (8 rows x 128B = 1KB)
    int r8 = lane >> 3, c8 = lane & 7;
    int sck = c8 ^ r8;                       // row&7 == r8
    gload_lds16(kb + (size_t)(j0 + w * 8 + r8) * DHEAD + sck * 8, Kd + (w * 8) * DHEAD);
    // V: wave w stages d-rows w*16..w*16+15 (16 rows x 64B = 1KB)
    int r4 = lane >> 2, c4 = lane & 3;
    int rowv = w * 16 + r4;
    int scv = c4 ^ (r4 & 3);                 // rowv&3 == r4&3
    gload_lds16(vb + (size_t)rowv * NSEQ + j0 + scv * 8, Vd + (w * 16) * KVB);
}

template<bool MASKT>
static __device__ __forceinline__ void attn_tile32(
        int j0, int q0, int g, int c0,
        const unsigned short* Kc, const unsigned short* Vc,
        s8 qf0, s8 qf1, unsigned short* plw,
        f4 o[4], float& m, f4& ol) {
    int sw = c0 & 7;
    int off0 = ((g ^ sw) << 3);
    int off1 = (((g + 4) ^ sw) << 3);
    f4 s[2];
    #pragma unroll
    for (int jt = 0; jt < 2; ++jt) {
        f4 acc; acc = 0.f;
        const unsigned short* kp = Kc + (jt * 16 + c0) * DHEAD;
        s8 kf0 = *(const s8*)(kp + off0);
        s8 kf1 = *(const s8*)(kp + off1);
        acc = __builtin_amdgcn_mfma_f32_16x16x32_bf16(kf0, qf0, acc, 0, 0, 0);
        acc = __builtin_amdgcn_mfma_f32_16x16x32_bf16(kf1, qf1, acc, 0, 0, 0);
        s[jt] = acc;
    }
    if (MASKT) {
        #pragma unroll
        for (int jt = 0; jt < 2; ++jt)
            #pragma unroll
            for (int r = 0; r < 4; ++r) {
                int j = j0 + jt * 16 + 4 * g + r;
                if (j > q0 + c0) s[jt][r] = -1e30f;
            }
    }
    f4 mv;
    #pragma unroll
    for (int r = 0; r < 4; ++r) mv[r] = fmaxf(s[0][r], s[1][r]);
    float mx = fmaxf(fmaxf(mv[0], mv[1]), fmaxf(mv[2], mv[3]));
    mx = fmaxf(mx, __shfl_xor(mx, 16));
    mx = fmaxf(mx, __shfl_xor(mx, 32));
    // deferred rescale, THR = 8*log2e ~= 11.5 (p bounded by ~e^8)
    if (__any(mx > m + 11.5f)) {
        float mnew = fmaxf(m, mx);
        float alpha = exp2f(m - mnew);
        #pragma unroll
        for (int dc = 0; dc < 4; ++dc)
            #pragma unroll
            for (int r = 0; r < 4; ++r) o[dc][r] *= alpha;
        #pragma unroll
        for (int r = 0; r < 4; ++r) ol[r] *= alpha;
        m = mnew;
    }
    // p = exp2(s - m) [libm], pack bf16, store to swizzled p_lds row c0:
    // logical shorts 16jt+4g (8B) = chunk 2jt+(g>>1), dword off (g&1)*2
    int swp = c0 & 3;
    #pragma unroll
    for (int jt = 0; jt < 2; ++jt) {
        f4 p;
        #pragma unroll
        for (int r = 0; r < 4; ++r) p[r] = exp2f(s[jt][r] - m);
        uint2 pk;
        pk.x = cvt_pk_bf16(p[0], p[1]);
        pk.y = cvt_pk_bf16(p[2], p[3]);
        int swc = (2 * jt + (g >> 1)) ^ swp;
        *(uint2*)(plw + c0 * KVB + swc * 8 + (g & 1) * 4) = pk;
    }
    // wave-synchronous fence for the cross-lane LDS transpose
    __builtin_amdgcn_sched_barrier(0);
    asm volatile("s_waitcnt lgkmcnt(0)" ::: "memory");
    __builtin_amdgcn_sched_barrier(0);
    // pf = logical chunk g of row c0 (j = 8g..8g+7)
    s8 pf = *(const s8*)(plw + c0 * KVB + ((g ^ swp) << 3));
    // l accumulation on the MFMA pipe: ol += 1-row * P^T
    const s8 onesf = {(short)0x3F80, (short)0x3F80, (short)0x3F80, (short)0x3F80,
                      (short)0x3F80, (short)0x3F80, (short)0x3F80, (short)0x3F80};
    ol = __builtin_amdgcn_mfma_f32_16x16x32_bf16(onesf, pf, ol, 0, 0, 0);
    #pragma unroll
    for (int dc = 0; dc < 4; ++dc) {
        // V row = dc*16+c0 (row&3 == c0&3), logical chunk g
        const unsigned short* vp = Vc + (dc * 16 + c0) * KVB + ((g ^ swp) << 3);
        s8 vf = *(const s8*)(vp);
        o[dc] = __builtin_amdgcn_mfma_f32_16x16x32_bf16(vf, pf, o[dc], 0, 0, 0);
    }
}

// grid 1024 (1D), block 256. Strict longest-first, XCD-owned bh:
//   xcd = bid&7; k = bid>>3 (0..127); qt = 31-(k>>2) [descending]; bh = xcd + 8*(k&3)
__global__ __launch_bounds__(256) void attn_kernel(
        const unsigned short* __restrict__ q_h, const unsigned short* __restrict__ k_h,
        const unsigned short* __restrict__ v_t, unsigned short* __restrict__ attn_out) {
    __shared__ unsigned short Ks[2][KVB * DHEAD];    // 2 x 4 KB
    __shared__ unsigned short Vs[2][DHEAD * KVB];    // 2 x 4 KB
    __shared__ unsigned short p_lds[4][16][KVB];     // 4 KB
    int tid = threadIdx.x, lane = tid & 63, w = tid >> 6;
    int g = lane >> 4, c0 = lane & 15;
    int bid = blockIdx.x;
    int k = bid >> 3;
    int qt = 31 - (k >> 2);
    int bh = (bid & 7) + ((k & 3) << 3);
    const unsigned short* qb = q_h + (size_t)bh * NSEQ * DHEAD;
    const unsigned short* kb = k_h + (size_t)bh * NSEQ * DHEAD;
    const unsigned short* vb = v_t + (size_t)bh * DHEAD * NSEQ;
    unsigned short* plw = &p_lds[w][0][0];
    int b = bh >> 4, h = bh & 15;
    int q0 = qt * 64 + w * 16;
    s8 qf0 = *(const s8*)(qb + (size_t)(q0 + c0) * DHEAD + 8 * g);
    s8 qf1 = *(const s8*)(qb + (size_t)(q0 + c0) * DHEAD + 32 + 8 * g);
    f4 o[4]; o[0] = 0.f; o[1] = 0.f; o[2] = 0.f; o[3] = 0.f;
    f4 ol; ol = 0.f;
    float m = -1e30f;
    int nt = 2 * qt + 2;
    int tmask = 2 * qt + (w >> 1);     // waves 0,1 mask at 2qt, skip last; 2,3 mask at 2qt+1
    stage_kv32(kb, vb, 0, Ks[0], Vs[0], w, lane);
    __syncthreads();
    for (int t = 0; t < nt; ++t) {
        const unsigned short* Kc = Ks[t & 1];
        const unsigned short* Vc = Vs[t & 1];
        if (t + 1 < nt)
            stage_kv32(kb, vb, (t + 1) * KVB, Ks[(t + 1) & 1], Vs[(t + 1) & 1], w, lane);
        if (t < tmask)
            attn_tile32<false>(t * KVB, q0, g, c0, Kc, Vc, qf0, qf1, plw, o, m, ol);
        else if (t == tmask)
            attn_tile32<true>(t * KVB, q0, g, c0, Kc, Vc, qf0, qf1, plw, o, m, ol);
        __syncthreads();
    }
    float invl = 1.0f / ol[0];
    unsigned short* dst = attn_out + ((size_t)(b * NSEQ) + q0 + c0) * (HEADS * DHEAD) + h * DHEAD;
    #pragma unroll
    for (int dc = 0; dc < 4; ++dc) {
        uint2 pk;
        pk.x = cvt_pk_bf16(o[dc][0] * invl, o[dc][1] * invl);
        pk.y = cvt_pk_bf16(o[dc][2] * invl, o[dc][3] * invl);
        *(uint2*)(dst + dc * 16 + 4 * g) = pk;
    }
}

// ---------------- out = attn @ Wo + bo (fp32 out), 64x128 tile.
// 1D grid 512, XCD-chunked. LDS-staged epilogue -> full-line fp32 writes.
__global__ __launch_bounds__(256) void gemm_o(
        const unsigned short* __restrict__ attn, const unsigned short* __restrict__ WoT,
        const float* __restrict__ bo, float* __restrict__ out) {
    __shared__ unsigned short As[3 * 64 * 32];
    __shared__ unsigned short Bs[3 * 128 * 32];
    __shared__ float tileF[64 * 132];   // stride 132 f32 = 528B (16B-mult)
    f4 acc[2][4];
    #pragma unroll
    for (int m = 0; m < 2; ++m)
        #pragma unroll
        for (int n = 0; n < 4; ++n) acc[m][n] = 0.f;
    int bid = blockIdx.x;
    int xcd = bid & 7;
    int kk = bid >> 3;              // 0..63
    int bx = kk & 7;
    int by = xcd * 8 + (kk >> 3);   // 0..63
    int bm0 = by * 64, bn0 = bx * 128;
    gemm_core64_p3(attn, WoT, bm0, bn0, As, Bs, acc);
    int tid = threadIdx.x;
    int lane = tid & 63, w = tid >> 6;
    int wr = w >> 1, wc = w & 1, g = lane >> 4, c0 = lane & 15;
    #pragma unroll
    for (int m = 0; m < 2; ++m)
        #pragma unroll
        for (int r = 0; r < 4; ++r) {
            int rowl = wr * 32 + m * 16 + 4 * g + r;
            #pragma unroll
            for (int n = 0; n < 4; ++n) {
                int col_l = wc * 64 + n * 16 + c0;
                tileF[rowl * 132 + col_l] = acc[m][n][r] + bo[bn0 + col_l];
            }
        }
    __syncthreads();
    #pragma unroll
    for (int i = 0; i < 8; ++i) {
        int L = i * 256 + tid;          // 2048 chunks: 64 rows x 32
        int rr = L >> 5, ch = L & 31;
        f4 v = *(const f4*)(tileF + rr * 132 + ch * 4);
        *(f4*)(out + (size_t)(bm0 + rr) * DIM + bn0 + ch * 4) = v;
    }
}

extern "C" void kernel_launch(void* const* d_in, const int* in_sizes, int n_in,
                              void* d_out, int out_size, void* d_ws, size_t ws_size,
                              hipStream_t stream) {
    const float* x     = (const float*)d_in[0];
    const float* freqs = (const float*)d_in[1];
    const float* gamma = (const float*)d_in[2];
    const float* Wq    = (const float*)d_in[3];
    const float* Wkv   = (const float*)d_in[4];
    const float* Wo    = (const float*)d_in[5];
    const float* bo    = (const float*)d_in[6];
    float* out = (float*)d_out;

    char* ws = (char*)d_ws;
    unsigned short* xn   = (unsigned short*)(ws + 0);          //  8 MB: 4096x1024 bf16
    unsigned short* WqT  = (unsigned short*)(ws + 8388608);    //  2 MB
    unsigned short* WkvT = (unsigned short*)(ws + 10485760);   //  4 MB
    unsigned short* WoT  = (unsigned short*)(ws + 14680064);   //  2 MB
    unsigned short* q_h  = (unsigned short*)(ws + 16777216);   //  8 MB (b,h,n,d)
    unsigned short* k_h  = (unsigned short*)(ws + 25165824);   //  8 MB (b,h,n,d)
    unsigned short* v_t  = (unsigned short*)(ws + 33554432);   //  8 MB (b,h,d,n)
    float*          cs   = (float*)(ws + 41943040);            // 512 KB cos/sin table
    unsigned short* attn = xn;   // xn dead after gemm_qkv; attn_out aliases it

    prep_rms_kernel<<<8704, 256, 0, stream>>>(x, gamma, Wq, Wkv, Wo, freqs,
                                              xn, WqT, WkvT, WoT, cs);
    gemm_qkv<<<1536, 256, 0, stream>>>(xn, WqT, WkvT, cs, q_h, k_h, v_t);
    attn_kernel<<<1024, 256, 0, stream>>>(q_h, k_h, v_t, attn);
    gemm_o  <<<512, 256, 0, stream>>>(attn, WoT, bo, out);
}

// Round 21
// 128.907 us; speedup vs baseline: 1.1253x; 1.1253x over previous
//
#include <hip/hip_runtime.h>
#include <hip/hip_bf16.h>
#include <math.h>

typedef short s8 __attribute__((ext_vector_type(8)));
typedef float f4 __attribute__((ext_vector_type(4)));

#define HEADS 16
#define DHEAD 64
#define NSEQ 2048
#define BATCH 2
#define DIM 1024
#define ROT 32
// Q scale: head_dim^-0.5 * log2(e)  (softmax done in exp2 domain, libm exp2f --
// fast v_exp variants are QUARANTINED: rounds 13/14/15/18 all failed with them)
#define QSCALE 0.18033688011112042f

static __device__ __forceinline__ unsigned short f2bf(float f) {
    union { float f; unsigned int u; } v; v.f = f;
    unsigned int u = v.u;
    unsigned int r = (u + 0x7FFFu + ((u >> 16) & 1u)) >> 16;
    return (unsigned short)r;
}

static __device__ __forceinline__ unsigned int cvt_pk_bf16(float lo, float hi) {
    unsigned int r;
    asm volatile("v_cvt_pk_bf16_f32 %0, %1, %2" : "=v"(r) : "v"(lo), "v"(hi));
    return r;
}

// async global->LDS, 16B per lane. LDS dest is wave-uniform base + lane*16 (HW).
static __device__ __forceinline__ void gload_lds16(
        const unsigned short* g, unsigned short* l) {
    __builtin_amdgcn_global_load_lds(
        (const __attribute__((address_space(1))) void*)g,
        (__attribute__((address_space(3))) void*)l,
        16, 0, 0);
}

// ---------------- fused prep + RMSNorm (independent memory-bound work, 1 dispatch)
static __device__ __forceinline__ void tr_tile(
        const float* __restrict__ in, unsigned short* __restrict__ out,
        int K, int N, int n0, int k0, int tid, float* tile /*32*33*/) {
    int tx = tid & 31, ty = tid >> 5;  // 32 x 8
    #pragma unroll
    for (int j = 0; j < 32; j += 8)
        tile[(ty + j) * 33 + tx] = in[(size_t)(k0 + ty + j) * N + n0 + tx];
    __syncthreads();
    #pragma unroll
    for (int j = 0; j < 32; j += 8)
        out[(size_t)(n0 + ty + j) * K + k0 + tx] = f2bf(tile[tx * 33 + ty + j]);
}

__global__ __launch_bounds__(256) void prep_rms_kernel(
        const float* __restrict__ x, const float* __restrict__ gamma,
        const float* __restrict__ Wq, const float* __restrict__ Wkv,
        const float* __restrict__ Wo, const float* __restrict__ freqs,
        unsigned short* __restrict__ xn, unsigned short* __restrict__ WqT,
        unsigned short* __restrict__ WkvT, unsigned short* __restrict__ WoT,
        float* __restrict__ cs) {
    __shared__ float smem[32 * 33];
    int bid = blockIdx.x, tid = threadIdx.x;
    if (bid < 4096) {
        int row = bid;
        float4 v = ((const float4*)(x + (size_t)row * DIM))[tid];
        float ss = v.x * v.x + v.y * v.y + v.z * v.z + v.w * v.w;
        #pragma unroll
        for (int m = 1; m < 64; m <<= 1) ss += __shfl_xor(ss, m, 64);
        int wave = tid >> 6;
        if ((tid & 63) == 0) smem[wave] = ss;
        __syncthreads();
        float total = smem[0] + smem[1] + smem[2] + smem[3];
        float norm = sqrtf(total * (1.0f / DIM));
        float inv = 1.0f / fmaxf(norm, 1e-8f);
        float4 g = ((const float4*)gamma)[tid];
        ushort4 o;
        o.x = f2bf(v.x * inv * g.x);
        o.y = f2bf(v.y * inv * g.y);
        o.z = f2bf(v.z * inv * g.z);
        o.w = f2bf(v.w * inv * g.w);
        ((ushort4*)(xn + (size_t)row * DIM))[tid] = o;
    } else if (bid < 5120) {
        int idx = bid - 4096;
        tr_tile(Wq, WqT, 1024, 1024, (idx & 31) * 32, (idx >> 5) * 32, tid, smem);
    } else if (bid < 7168) {
        int idx = bid - 5120;
        tr_tile(Wkv, WkvT, 1024, 2048, (idx & 63) * 32, (idx >> 6) * 32, tid, smem);
    } else if (bid < 8192) {
        int idx = bid - 7168;
        tr_tile(Wo, WoT, 1024, 1024, (idx & 31) * 32, (idx >> 5) * 32, tid, smem);
    } else {
        int i = (bid - 8192) * 256 + tid;   // 512*256 = 2048*64
        int npos = i >> 6, j = i & 63;
        int q = j >> 4;
        int fi = (q >> 1) * 16 + (j & 15);
        float f = freqs[npos * ROT + fi];
        cs[i] = (q & 1) ? sinf(f) : cosf(f);
    }
}

// ---------------- GEMM core: block 64x128, 4 waves 2x2, wave 32x64 = acc[2][4].
// K=1024, BK=32, 3-deep counted-vmcnt pipeline (T3+T4).
static __device__ __forceinline__ void gemm_core64_p3(
        const unsigned short* __restrict__ A, const unsigned short* __restrict__ BT,
        int bm0, int bn0, unsigned short* As, unsigned short* Bs, f4 acc[2][4]) {
    const int Kd = DIM;
    int tid = threadIdx.x, lane = tid & 63, w = tid >> 6;
    int wr = w >> 1, wc = w & 1;
    int r16 = lane & 15, g8 = 8 * (lane >> 4);
    int srow = lane >> 2, scol = (lane & 3) * 8;
    const unsigned short* Ag0 = A  + (size_t)(bm0 + w * 16 + srow) * Kd + scol;
    const unsigned short* Bg0 = BT + (size_t)(bn0 + (w * 2 + 0) * 16 + srow) * Kd + scol;
    const unsigned short* Bg1 = BT + (size_t)(bn0 + (w * 2 + 1) * 16 + srow) * Kd + scol;
    unsigned short* Al  = As + w * 512;
    unsigned short* Bl0 = Bs + (w * 2 + 0) * 512;
    unsigned short* Bl1 = Bs + (w * 2 + 1) * 512;
    const unsigned short* ar = As + (wr * 32 + r16) * 32 + g8;
    const unsigned short* br = Bs + (wc * 64 + r16) * 32 + g8;
    #pragma unroll
    for (int p = 0; p < 3; ++p) {
        int k0 = p * 32;
        gload_lds16(Ag0 + k0, Al + p * 2048);
        gload_lds16(Bg0 + k0, Bl0 + p * 4096);
        gload_lds16(Bg1 + k0, Bl1 + p * 4096);
    }
    asm volatile("s_waitcnt vmcnt(6)" ::: "memory");
    __builtin_amdgcn_s_barrier();
    __builtin_amdgcn_sched_barrier(0);
    #pragma unroll
    for (int t = 0; t < 32; ++t) {
        const int cb = t % 3;
        const int aoff = cb * 2048;
        const int boff = cb * 4096;
        {
            s8 a0 = *(const s8*)(ar + aoff);
            s8 a1 = *(const s8*)(ar + aoff + 512);
            s8 b0 = *(const s8*)(br + boff);
            s8 b1 = *(const s8*)(br + boff + 512);
            s8 b2 = *(const s8*)(br + boff + 1024);
            s8 b3 = *(const s8*)(br + boff + 1536);
            acc[0][0] = __builtin_amdgcn_mfma_f32_16x16x32_bf16(a0, b0, acc[0][0], 0, 0, 0);
            acc[0][1] = __builtin_amdgcn_mfma_f32_16x16x32_bf16(a0, b1, acc[0][1], 0, 0, 0);
            acc[0][2] = __builtin_amdgcn_mfma_f32_16x16x32_bf16(a0, b2, acc[0][2], 0, 0, 0);
            acc[0][3] = __builtin_amdgcn_mfma_f32_16x16x32_bf16(a0, b3, acc[0][3], 0, 0, 0);
            acc[1][0] = __builtin_amdgcn_mfma_f32_16x16x32_bf16(a1, b0, acc[1][0], 0, 0, 0);
            acc[1][1] = __builtin_amdgcn_mfma_f32_16x16x32_bf16(a1, b1, acc[1][1], 0, 0, 0);
            acc[1][2] = __builtin_amdgcn_mfma_f32_16x16x32_bf16(a1, b2, acc[1][2], 0, 0, 0);
            acc[1][3] = __builtin_amdgcn_mfma_f32_16x16x32_bf16(a1, b3, acc[1][3], 0, 0, 0);
        }
        __builtin_amdgcn_sched_barrier(0);
        __builtin_amdgcn_s_barrier();
        if (t + 3 < 32) {
            int k3 = (t + 3) * 32;
            gload_lds16(Ag0 + k3, Al + aoff);
            gload_lds16(Bg0 + k3, Bl0 + boff);
            gload_lds16(Bg1 + k3, Bl1 + boff);
        }
        if (t + 1 < 32) {
            if (t + 3 < 32)      { asm volatile("s_waitcnt vmcnt(6)" ::: "memory"); }
            else if (t + 2 < 32) { asm volatile("s_waitcnt vmcnt(3)" ::: "memory"); }
            else                 { asm volatile("s_waitcnt vmcnt(0)" ::: "memory"); }
            __builtin_amdgcn_s_barrier();
            __builtin_amdgcn_sched_barrier(0);
        }
    }
}

// ---------------- fused QKV projection. 1D grid 1536, XCD-chunked (T1).
// Epilogues stage the 64x128 output tile in LDS (reusing Bs; K-loop ends on a
// barrier), then write FULL 128B cache lines cooperatively -> no RFO fills.
__global__ __launch_bounds__(256) void gemm_qkv(
        const unsigned short* __restrict__ xn, const unsigned short* __restrict__ WqT,
        const unsigned short* __restrict__ WkvT, const float* __restrict__ cs,
        unsigned short* __restrict__ q_h, unsigned short* __restrict__ k_h,
        unsigned short* __restrict__ v_t) {
    __shared__ unsigned short As[3 * 64 * 32];
    __shared__ unsigned short Bs[3 * 128 * 32];
    f4 acc[2][4];
    #pragma unroll
    for (int m = 0; m < 2; ++m)
        #pragma unroll
        for (int n = 0; n < 4; ++n) acc[m][n] = 0.f;
    int bid = blockIdx.x;
    int xcd = bid & 7;
    int kk = bid >> 3;                 // 0..191
    int rx = xcd >> 2, ry = xcd & 3;   // region: 2 x 4
    int bx = rx * 12 + (kk % 12);      // 0..23
    int by = ry * 16 + (kk / 12);      // 0..63
    bool isq = (bx < 8);
    int bm0 = by * 64;
    int bn0 = (isq ? bx : (bx - 8)) * 128;
    gemm_core64_p3(xn, isq ? WqT : WkvT, bm0, bn0, As, Bs, acc);
    int tid = threadIdx.x;
    int lane = tid & 63, w = tid >> 6;
    int wr = w >> 1, wc = w & 1, g = lane >> 4, c0 = lane & 15;
    unsigned short* tile = Bs;          // safe: K-loop ended on a barrier
    int b_blk = bm0 >> 11;
    int nbase = bm0 & 2047;             // batch-folded sequence base
    if (isq) {
        #pragma unroll
        for (int m = 0; m < 2; ++m)
            #pragma unroll
            for (int r = 0; r < 4; ++r) {
                int rowl = wr * 32 + m * 16 + 4 * g + r;
                int npos = nbase + rowl;
                const float* csr = cs + npos * 64;
                float a0 = acc[m][0][r] * QSCALE;
                float a1 = acc[m][1][r] * QSCALE;
                float q0 = a0 * csr[c0] - a1 * csr[16 + c0];
                float q1 = a1 * csr[32 + c0] + a0 * csr[48 + c0];
                unsigned short* trow = tile + rowl * 128 + wc * 64;
                trow[c0]      = f2bf(q0);
                trow[16 + c0] = f2bf(q1);
                trow[32 + c0] = f2bf(acc[m][2][r] * QSCALE);
                trow[48 + c0] = f2bf(acc[m][3][r] * QSCALE);
            }
        __syncthreads();
        #pragma unroll
        for (int i = 0; i < 4; ++i) {
            int L = i * 256 + tid;
            int rr = L >> 4, hh = (L >> 3) & 1, ch = L & 7;
            int npos = nbase + rr;
            s8 v = *(const s8*)(tile + rr * 128 + hh * 64 + ch * 8);
            *(s8*)(q_h + ((size_t)(b_blk * HEADS + 2 * bx + hh) * NSEQ + npos) * DHEAD + ch * 8) = v;
        }
    } else if (bx < 16) {
        #pragma unroll
        for (int m = 0; m < 2; ++m)
            #pragma unroll
            for (int r = 0; r < 4; ++r) {
                int rowl = wr * 32 + m * 16 + 4 * g + r;
                int npos = nbase + rowl;
                const float* csr = cs + npos * 64;
                float a0 = acc[m][0][r], a1 = acc[m][1][r];
                float k0v = a0 * csr[c0] - a1 * csr[16 + c0];
                float k1v = a1 * csr[32 + c0] + a0 * csr[48 + c0];
                unsigned short* trow = tile + rowl * 128 + wc * 64;
                trow[c0]      = f2bf(k0v);
                trow[16 + c0] = f2bf(k1v);
                trow[32 + c0] = f2bf(acc[m][2][r]);
                trow[48 + c0] = f2bf(acc[m][3][r]);
            }
        __syncthreads();
        #pragma unroll
        for (int i = 0; i < 4; ++i) {
            int L = i * 256 + tid;
            int rr = L >> 4, hh = (L >> 3) & 1, ch = L & 7;
            int npos = nbase + rr;
            s8 v = *(const s8*)(tile + rr * 128 + hh * 64 + ch * 8);
            *(s8*)(k_h + ((size_t)(b_blk * HEADS + 2 * (bx - 8) + hh) * NSEQ + npos) * DHEAD + ch * 8) = v;
        }
    } else {
        // V: tile[col][row] with stride 72 shorts (144B: 16B-aligned, bank-spread)
        #pragma unroll
        for (int m = 0; m < 2; ++m) {
            int r0 = wr * 32 + m * 16 + 4 * g;
            #pragma unroll
            for (int n = 0; n < 4; ++n) {
                int col = wc * 64 + n * 16 + c0;
                uint2 pk;
                pk.x = cvt_pk_bf16(acc[m][n][0], acc[m][n][1]);
                pk.y = cvt_pk_bf16(acc[m][n][2], acc[m][n][3]);
                *(uint2*)(tile + col * 72 + r0) = pk;
            }
        }
        __syncthreads();
        #pragma unroll
        for (int i = 0; i < 4; ++i) {
            int L = i * 256 + tid;          // 1024 chunks: 128 cols x 8
            int col = L >> 3, ch = L & 7;
            int h = 2 * (bx - 16) + (col >> 6);
            int d = col & 63;
            s8 v = *(const s8*)(tile + col * 72 + ch * 8);
            *(s8*)(v_t + ((size_t)(b_blk * HEADS + h) * DHEAD + d) * NSEQ + nbase + ch * 8) = v;
        }
    }
}

// ---------------- causal flash attention: 8-wave blocks, 128-row q-tiles ----
// K/V KVB=64 double-buffer shared by 8 waves; p_lds per-wave [16][64]
// chunk-XOR swizzle (r19-verified). LDS 48 KB -> 2 blocks/CU, 16 waves/CU.

static __device__ __forceinline__ void stage_kv64_8w(
        const unsigned short* __restrict__ kb, const unsigned short* __restrict__ vb,
        int j0, unsigned short* Kd, unsigned short* Vd, int w, int lane) {
    int r8 = lane >> 3, c = lane & 7;
    int sc = c ^ r8;                  // inverse swizzle: row&7 == r8 (base w*8 is 8-aligned)
    int rb = w * 8;                   // wave-uniform row base
    gload_lds16(kb + (size_t)(j0 + rb + r8) * DHEAD + sc * 8, Kd + rb * DHEAD);
    gload_lds16(vb + (size_t)(rb + r8) * NSEQ + j0 + sc * 8,  Vd + rb * DHEAD);
}

template<bool MASKT>
static __device__ __forceinline__ void attn_tile_lds(
        int j0, int q0, int g, int c0, int njt,
        const unsigned short* Kc, const unsigned short* Vc,
        s8 qf0, s8 qf1, unsigned short* plw,
        f4 o[4], float& m, f4& ol) {
    int sw = c0 & 7;
    int off0 = ((g ^ sw) << 3);
    int off1 = (((g + 4) ^ sw) << 3);
    f4 s[4];
    #pragma unroll
    for (int jt = 0; jt < 4; ++jt) {
        f4 acc; acc = 0.f;
        if (!MASKT || jt < njt) {
            const unsigned short* kp = Kc + (jt * 16 + c0) * DHEAD;
            s8 kf0 = *(const s8*)(kp + off0);
            s8 kf1 = *(const s8*)(kp + off1);
            acc = __builtin_amdgcn_mfma_f32_16x16x32_bf16(kf0, qf0, acc, 0, 0, 0);
            acc = __builtin_amdgcn_mfma_f32_16x16x32_bf16(kf1, qf1, acc, 0, 0, 0);
        }
        s[jt] = acc;
    }
    if (MASKT) {
        #pragma unroll
        for (int jt = 0; jt < 4; ++jt)
            #pragma unroll
            for (int r = 0; r < 4; ++r) {
                int j = j0 + jt * 16 + 4 * g + r;
                if (j > q0 + c0) s[jt][r] = -1e30f;
            }
    }
    f4 mv;
    #pragma unroll
    for (int r = 0; r < 4; ++r)
        mv[r] = fmaxf(fmaxf(s[0][r], s[1][r]), fmaxf(s[2][r], s[3][r]));
    float mx = fmaxf(fmaxf(mv[0], mv[1]), fmaxf(mv[2], mv[3]));
    mx = fmaxf(mx, __shfl_xor(mx, 16));
    mx = fmaxf(mx, __shfl_xor(mx, 32));
    // deferred rescale, THR = 8*log2e ~= 11.5 (p bounded by ~e^8)
    if (__any(mx > m + 11.5f)) {
        float mnew = fmaxf(m, mx);
        float alpha = exp2f(m - mnew);
        #pragma unroll
        for (int dc = 0; dc < 4; ++dc)
            #pragma unroll
            for (int r = 0; r < 4; ++r) o[dc][r] *= alpha;
        #pragma unroll
        for (int r = 0; r < 4; ++r) ol[r] *= alpha;
        m = mnew;
    }
    // p = exp2(s - m) [libm], pack bf16, store to swizzled p_lds row c0:
    // logical shorts jt*16+4g (8B) = chunk 2jt+(g>>1), off (g&1)*4 shorts
    #pragma unroll
    for (int jt = 0; jt < 4; ++jt) {
        f4 p;
        #pragma unroll
        for (int r = 0; r < 4; ++r) p[r] = exp2f(s[jt][r] - m);
        uint2 pk;
        pk.x = cvt_pk_bf16(p[0], p[1]);
        pk.y = cvt_pk_bf16(p[2], p[3]);
        int swc = (2 * jt + (g >> 1)) ^ sw;
        *(uint2*)(plw + c0 * 64 + swc * 8 + (g & 1) * 4) = pk;
    }
    // wave-synchronous fence for the cross-lane LDS transpose
    __builtin_amdgcn_sched_barrier(0);
    asm volatile("s_waitcnt lgkmcnt(0)" ::: "memory");
    __builtin_amdgcn_sched_barrier(0);
    // reads: pf0 = logical chunk g, pf1 = logical chunk 4+g (swizzled)
    s8 pf0 = *(const s8*)(plw + c0 * 64 + ((g ^ sw) << 3));
    s8 pf1 = *(const s8*)(plw + c0 * 64 + (((4 + g) ^ sw) << 3));
    bool hi_half = (!MASKT) || (njt > 2);
    // l accumulation on the MFMA pipe: ol += 1-row * P^T
    const s8 onesf = {(short)0x3F80, (short)0x3F80, (short)0x3F80, (short)0x3F80,
                      (short)0x3F80, (short)0x3F80, (short)0x3F80, (short)0x3F80};
    ol = __builtin_amdgcn_mfma_f32_16x16x32_bf16(onesf, pf0, ol, 0, 0, 0);
    if (hi_half)
        ol = __builtin_amdgcn_mfma_f32_16x16x32_bf16(onesf, pf1, ol, 0, 0, 0);
    #pragma unroll
    for (int dc = 0; dc < 4; ++dc) {
        const unsigned short* vp = Vc + (dc * 16 + c0) * DHEAD;
        s8 vf0 = *(const s8*)(vp + off0);
        o[dc] = __builtin_amdgcn_mfma_f32_16x16x32_bf16(vf0, pf0, o[dc], 0, 0, 0);
        if (hi_half) {
            s8 vf1 = *(const s8*)(vp + off1);
            o[dc] = __builtin_amdgcn_mfma_f32_16x16x32_bf16(vf1, pf1, o[dc], 0, 0, 0);
        }
    }
}

// grid 512 (1D), block 512 (8 waves). Strict longest-first, XCD-owned bh:
//   xcd = bid&7; k = bid>>3 (0..63); qt = 15-(k>>2) [descending]; bh = xcd + 8*(k&3)
// Wave w owns q rows qt*128 + w*16 .. +15. nt = 2qt+2 tiles of 64.
// tmask_w = 2qt + (w>>2): waves 0-3 mask at 2qt (skip last), 4-7 at 2qt+1.
__global__ __launch_bounds__(512) void attn_kernel(
        const unsigned short* __restrict__ q_h, const unsigned short* __restrict__ k_h,
        const unsigned short* __restrict__ v_t, unsigned short* __restrict__ attn_out) {
    __shared__ unsigned short Ks[2][64 * DHEAD];     // 2 x 8 KB
    __shared__ unsigned short Vs[2][64 * DHEAD];     // 2 x 8 KB
    __shared__ unsigned short p_lds[8][16][64];      // 16 KB
    int tid = threadIdx.x, lane = tid & 63, w = tid >> 6;
    int g = lane >> 4, c0 = lane & 15;
    int bid = blockIdx.x;
    int k = bid >> 3;
    int qt = 15 - (k >> 2);
    int bh = (bid & 7) + ((k & 3) << 3);
    const unsigned short* qb = q_h + (size_t)bh * NSEQ * DHEAD;
    const unsigned short* kb = k_h + (size_t)bh * NSEQ * DHEAD;
    const unsigned short* vb = v_t + (size_t)bh * DHEAD * NSEQ;
    unsigned short* plw = &p_lds[w][0][0];
    int b = bh >> 4, h = bh & 15;
    int q0 = qt * 128 + w * 16;
    s8 qf0 = *(const s8*)(qb + (size_t)(q0 + c0) * DHEAD + 8 * g);
    s8 qf1 = *(const s8*)(qb + (size_t)(q0 + c0) * DHEAD + 32 + 8 * g);
    f4 o[4]; o[0] = 0.f; o[1] = 0.f; o[2] = 0.f; o[3] = 0.f;
    f4 ol; ol = 0.f;
    float m = -1e30f;
    int nt = 2 * qt + 2;
    int tmask = 2 * qt + (w >> 2);
    stage_kv64_8w(kb, vb, 0, Ks[0], Vs[0], w, lane);
    __syncthreads();
    for (int t = 0; t < nt; ++t) {
        const unsigned short* Kc = Ks[t & 1];
        const unsigned short* Vc = Vs[t & 1];
        if (t + 1 < nt)
            stage_kv64_8w(kb, vb, (t + 1) * 64, Ks[(t + 1) & 1], Vs[(t + 1) & 1], w, lane);
        if (t < tmask)
            attn_tile_lds<false>(t * 64, q0, g, c0, 4, Kc, Vc, qf0, qf1, plw, o, m, ol);
        else if (t == tmask)
            attn_tile_lds<true>(t * 64, q0, g, c0, 4, Kc, Vc, qf0, qf1, plw, o, m, ol);
        __syncthreads();
    }
    float invl = 1.0f / ol[0];
    unsigned short* dst = attn_out + ((size_t)(b * NSEQ) + q0 + c0) * (HEADS * DHEAD) + h * DHEAD;
    #pragma unroll
    for (int dc = 0; dc < 4; ++dc) {
        uint2 pk;
        pk.x = cvt_pk_bf16(o[dc][0] * invl, o[dc][1] * invl);
        pk.y = cvt_pk_bf16(o[dc][2] * invl, o[dc][3] * invl);
        *(uint2*)(dst + dc * 16 + 4 * g) = pk;
    }
}

// ---------------- out = attn @ Wo + bo (fp32 out), 64x128 tile.
// 1D grid 512, XCD-chunked. LDS-staged epilogue -> full-line fp32 writes.
__global__ __launch_bounds__(256) void gemm_o(
        const unsigned short* __restrict__ attn, const unsigned short* __restrict__ WoT,
        const float* __restrict__ bo, float* __restrict__ out) {
    __shared__ unsigned short As[3 * 64 * 32];
    __shared__ unsigned short Bs[3 * 128 * 32];
    __shared__ float tileF[64 * 132];   // stride 132 f32 = 528B (16B-mult)
    f4 acc[2][4];
    #pragma unroll
    for (int m = 0; m < 2; ++m)
        #pragma unroll
        for (int n = 0; n < 4; ++n) acc[m][n] = 0.f;
    int bid = blockIdx.x;
    int xcd = bid & 7;
    int kk = bid >> 3;              // 0..63
    int bx = kk & 7;
    int by = xcd * 8 + (kk >> 3);   // 0..63
    int bm0 = by * 64, bn0 = bx * 128;
    gemm_core64_p3(attn, WoT, bm0, bn0, As, Bs, acc);
    int tid = threadIdx.x;
    int lane = tid & 63, w = tid >> 6;
    int wr = w >> 1, wc = w & 1, g = lane >> 4, c0 = lane & 15;
    #pragma unroll
    for (int m = 0; m < 2; ++m)
        #pragma unroll
        for (int r = 0; r < 4; ++r) {
            int rowl = wr * 32 + m * 16 + 4 * g + r;
            #pragma unroll
            for (int n = 0; n < 4; ++n) {
                int col_l = wc * 64 + n * 16 + c0;
                tileF[rowl * 132 + col_l] = acc[m][n][r] + bo[bn0 + col_l];
            }
        }
    __syncthreads();
    #pragma unroll
    for (int i = 0; i < 8; ++i) {
        int L = i * 256 + tid;          // 2048 chunks: 64 rows x 32
        int rr = L >> 5, ch = L & 31;
        f4 v = *(const f4*)(tileF + rr * 132 + ch * 4);
        *(f4*)(out + (size_t)(bm0 + rr) * DIM + bn0 + ch * 4) = v;
    }
}

extern "C" void kernel_launch(void* const* d_in, const int* in_sizes, int n_in,
                              void* d_out, int out_size, void* d_ws, size_t ws_size,
                              hipStream_t stream) {
    const float* x     = (const float*)d_in[0];
    const float* freqs = (const float*)d_in[1];
    const float* gamma = (const float*)d_in[2];
    const float* Wq    = (const float*)d_in[3];
    const float* Wkv   = (const float*)d_in[4];
    const float* Wo    = (const float*)d_in[5];
    const float* bo    = (const float*)d_in[6];
    float* out = (float*)d_out;

    char* ws = (char*)d_ws;
    unsigned short* xn   = (unsigned short*)(ws + 0);          //  8 MB: 4096x1024 bf16
    unsigned short* WqT  = (unsigned short*)(ws + 8388608);    //  2 MB
    unsigned short* WkvT = (unsigned short*)(ws + 10485760);   //  4 MB
    unsigned short* WoT  = (unsigned short*)(ws + 14680064);   //  2 MB
    unsigned short* q_h  = (unsigned short*)(ws + 16777216);   //  8 MB (b,h,n,d)
    unsigned short* k_h  = (unsigned short*)(ws + 25165824);   //  8 MB (b,h,n,d)
    unsigned short* v_t  = (unsigned short*)(ws + 33554432);   //  8 MB (b,h,d,n)
    float*          cs   = (float*)(ws + 41943040);            // 512 KB cos/sin table
    unsigned short* attn = xn;   // xn dead after gemm_qkv; attn_out aliases it

    prep_rms_kernel<<<8704, 256, 0, stream>>>(x, gamma, Wq, Wkv, Wo, freqs,
                                              xn, WqT, WkvT, WoT, cs);
    gemm_qkv<<<1536, 256, 0, stream>>>(xn, WqT, WkvT, cs, q_h, k_h, v_t);
    attn_kernel<<<512, 512, 0, stream>>>(q_h, k_h, v_t, attn);
    gemm_o  <<<512, 256, 0, stream>>>(attn, WoT, bo, out);
}

// Round 22
// 124.558 us; speedup vs baseline: 1.1646x; 1.0349x over previous
//
#include <hip/hip_runtime.h>
#include <hip/hip_bf16.h>
#include <math.h>

typedef short s8 __attribute__((ext_vector_type(8)));
typedef float f4 __attribute__((ext_vector_type(4)));

#define HEADS 16
#define DHEAD 64
#define NSEQ 2048
#define BATCH 2
#define DIM 1024
#define ROT 32
// Q scale: head_dim^-0.5 * log2(e)  (softmax done in exp2 domain, libm exp2f --
// fast v_exp variants are QUARANTINED: rounds 13/14/15/18 all failed with them)
#define QSCALE 0.18033688011112042f

static __device__ __forceinline__ unsigned short f2bf(float f) {
    union { float f; unsigned int u; } v; v.f = f;
    unsigned int u = v.u;
    unsigned int r = (u + 0x7FFFu + ((u >> 16) & 1u)) >> 16;
    return (unsigned short)r;
}

static __device__ __forceinline__ unsigned int cvt_pk_bf16(float lo, float hi) {
    unsigned int r;
    asm volatile("v_cvt_pk_bf16_f32 %0, %1, %2" : "=v"(r) : "v"(lo), "v"(hi));
    return r;
}

// async global->LDS, 16B per lane. LDS dest is wave-uniform base + lane*16 (HW).
static __device__ __forceinline__ void gload_lds16(
        const unsigned short* g, unsigned short* l) {
    __builtin_amdgcn_global_load_lds(
        (const __attribute__((address_space(1))) void*)g,
        (__attribute__((address_space(3))) void*)l,
        16, 0, 0);
}

// ---------------- fused prep + RMSNorm (independent memory-bound work, 1 dispatch)
static __device__ __forceinline__ void tr_tile(
        const float* __restrict__ in, unsigned short* __restrict__ out,
        int K, int N, int n0, int k0, int tid, float* tile /*32*33*/) {
    int tx = tid & 31, ty = tid >> 5;  // 32 x 8
    #pragma unroll
    for (int j = 0; j < 32; j += 8)
        tile[(ty + j) * 33 + tx] = in[(size_t)(k0 + ty + j) * N + n0 + tx];
    __syncthreads();
    #pragma unroll
    for (int j = 0; j < 32; j += 8)
        out[(size_t)(n0 + ty + j) * K + k0 + tx] = f2bf(tile[tx * 33 + ty + j]);
}

__global__ __launch_bounds__(256) void prep_rms_kernel(
        const float* __restrict__ x, const float* __restrict__ gamma,
        const float* __restrict__ Wq, const float* __restrict__ Wkv,
        const float* __restrict__ Wo, const float* __restrict__ freqs,
        unsigned short* __restrict__ xn, unsigned short* __restrict__ WqT,
        unsigned short* __restrict__ WkvT, unsigned short* __restrict__ WoT,
        float* __restrict__ cs) {
    __shared__ float smem[32 * 33];
    int bid = blockIdx.x, tid = threadIdx.x;
    if (bid < 4096) {
        int row = bid;
        float4 v = ((const float4*)(x + (size_t)row * DIM))[tid];
        float ss = v.x * v.x + v.y * v.y + v.z * v.z + v.w * v.w;
        #pragma unroll
        for (int m = 1; m < 64; m <<= 1) ss += __shfl_xor(ss, m, 64);
        int wave = tid >> 6;
        if ((tid & 63) == 0) smem[wave] = ss;
        __syncthreads();
        float total = smem[0] + smem[1] + smem[2] + smem[3];
        float norm = sqrtf(total * (1.0f / DIM));
        float inv = 1.0f / fmaxf(norm, 1e-8f);
        float4 g = ((const float4*)gamma)[tid];
        ushort4 o;
        o.x = f2bf(v.x * inv * g.x);
        o.y = f2bf(v.y * inv * g.y);
        o.z = f2bf(v.z * inv * g.z);
        o.w = f2bf(v.w * inv * g.w);
        ((ushort4*)(xn + (size_t)row * DIM))[tid] = o;
    } else if (bid < 5120) {
        int idx = bid - 4096;
        tr_tile(Wq, WqT, 1024, 1024, (idx & 31) * 32, (idx >> 5) * 32, tid, smem);
    } else if (bid < 7168) {
        int idx = bid - 5120;
        tr_tile(Wkv, WkvT, 1024, 2048, (idx & 63) * 32, (idx >> 6) * 32, tid, smem);
    } else if (bid < 8192) {
        int idx = bid - 7168;
        tr_tile(Wo, WoT, 1024, 1024, (idx & 31) * 32, (idx >> 5) * 32, tid, smem);
    } else {
        int i = (bid - 8192) * 256 + tid;   // 512*256 = 2048*64
        int npos = i >> 6, j = i & 63;
        int q = j >> 4;
        int fi = (q >> 1) * 16 + (j & 15);
        float f = freqs[npos * ROT + fi];
        cs[i] = (q & 1) ? sinf(f) : cosf(f);
    }
}

// ---------------- GEMM core: block 64x128, 4 waves 2x2, wave 32x64 = acc[2][4].
// K=1024, BK=32, 3-deep counted-vmcnt pipeline (T3+T4).
static __device__ __forceinline__ void gemm_core64_p3(
        const unsigned short* __restrict__ A, const unsigned short* __restrict__ BT,
        int bm0, int bn0, unsigned short* As, unsigned short* Bs, f4 acc[2][4]) {
    const int Kd = DIM;
    int tid = threadIdx.x, lane = tid & 63, w = tid >> 6;
    int wr = w >> 1, wc = w & 1;
    int r16 = lane & 15, g8 = 8 * (lane >> 4);
    int srow = lane >> 2, scol = (lane & 3) * 8;
    const unsigned short* Ag0 = A  + (size_t)(bm0 + w * 16 + srow) * Kd + scol;
    const unsigned short* Bg0 = BT + (size_t)(bn0 + (w * 2 + 0) * 16 + srow) * Kd + scol;
    const unsigned short* Bg1 = BT + (size_t)(bn0 + (w * 2 + 1) * 16 + srow) * Kd + scol;
    unsigned short* Al  = As + w * 512;
    unsigned short* Bl0 = Bs + (w * 2 + 0) * 512;
    unsigned short* Bl1 = Bs + (w * 2 + 1) * 512;
    const unsigned short* ar = As + (wr * 32 + r16) * 32 + g8;
    const unsigned short* br = Bs + (wc * 64 + r16) * 32 + g8;
    #pragma unroll
    for (int p = 0; p < 3; ++p) {
        int k0 = p * 32;
        gload_lds16(Ag0 + k0, Al + p * 2048);
        gload_lds16(Bg0 + k0, Bl0 + p * 4096);
        gload_lds16(Bg1 + k0, Bl1 + p * 4096);
    }
    asm volatile("s_waitcnt vmcnt(6)" ::: "memory");
    __builtin_amdgcn_s_barrier();
    __builtin_amdgcn_sched_barrier(0);
    #pragma unroll
    for (int t = 0; t < 32; ++t) {
        const int cb = t % 3;
        const int aoff = cb * 2048;
        const int boff = cb * 4096;
        {
            s8 a0 = *(const s8*)(ar + aoff);
            s8 a1 = *(const s8*)(ar + aoff + 512);
            s8 b0 = *(const s8*)(br + boff);
            s8 b1 = *(const s8*)(br + boff + 512);
            s8 b2 = *(const s8*)(br + boff + 1024);
            s8 b3 = *(const s8*)(br + boff + 1536);
            acc[0][0] = __builtin_amdgcn_mfma_f32_16x16x32_bf16(a0, b0, acc[0][0], 0, 0, 0);
            acc[0][1] = __builtin_amdgcn_mfma_f32_16x16x32_bf16(a0, b1, acc[0][1], 0, 0, 0);
            acc[0][2] = __builtin_amdgcn_mfma_f32_16x16x32_bf16(a0, b2, acc[0][2], 0, 0, 0);
            acc[0][3] = __builtin_amdgcn_mfma_f32_16x16x32_bf16(a0, b3, acc[0][3], 0, 0, 0);
            acc[1][0] = __builtin_amdgcn_mfma_f32_16x16x32_bf16(a1, b0, acc[1][0], 0, 0, 0);
            acc[1][1] = __builtin_amdgcn_mfma_f32_16x16x32_bf16(a1, b1, acc[1][1], 0, 0, 0);
            acc[1][2] = __builtin_amdgcn_mfma_f32_16x16x32_bf16(a1, b2, acc[1][2], 0, 0, 0);
            acc[1][3] = __builtin_amdgcn_mfma_f32_16x16x32_bf16(a1, b3, acc[1][3], 0, 0, 0);
        }
        __builtin_amdgcn_sched_barrier(0);
        __builtin_amdgcn_s_barrier();
        if (t + 3 < 32) {
            int k3 = (t + 3) * 32;
            gload_lds16(Ag0 + k3, Al + aoff);
            gload_lds16(Bg0 + k3, Bl0 + boff);
            gload_lds16(Bg1 + k3, Bl1 + boff);
        }
        if (t + 1 < 32) {
            if (t + 3 < 32)      { asm volatile("s_waitcnt vmcnt(6)" ::: "memory"); }
            else if (t + 2 < 32) { asm volatile("s_waitcnt vmcnt(3)" ::: "memory"); }
            else                 { asm volatile("s_waitcnt vmcnt(0)" ::: "memory"); }
            __builtin_amdgcn_s_barrier();
            __builtin_amdgcn_sched_barrier(0);
        }
    }
}

// ---------------- fused QKV projection. 1D grid 1536, XCD-chunked (T1).
// Epilogues stage the 64x128 output tile in LDS (reusing Bs; K-loop ends on a
// barrier), then write FULL 128B cache lines cooperatively -> no RFO fills.
__global__ __launch_bounds__(256) void gemm_qkv(
        const unsigned short* __restrict__ xn, const unsigned short* __restrict__ WqT,
        const unsigned short* __restrict__ WkvT, const float* __restrict__ cs,
        unsigned short* __restrict__ q_h, unsigned short* __restrict__ k_h,
        unsigned short* __restrict__ v_t) {
    __shared__ unsigned short As[3 * 64 * 32];
    __shared__ unsigned short Bs[3 * 128 * 32];
    f4 acc[2][4];
    #pragma unroll
    for (int m = 0; m < 2; ++m)
        #pragma unroll
        for (int n = 0; n < 4; ++n) acc[m][n] = 0.f;
    int bid = blockIdx.x;
    int xcd = bid & 7;
    int kk = bid >> 3;                 // 0..191
    int rx = xcd >> 2, ry = xcd & 3;   // region: 2 x 4
    int bx = rx * 12 + (kk % 12);      // 0..23
    int by = ry * 16 + (kk / 12);      // 0..63
    bool isq = (bx < 8);
    int bm0 = by * 64;
    int bn0 = (isq ? bx : (bx - 8)) * 128;
    gemm_core64_p3(xn, isq ? WqT : WkvT, bm0, bn0, As, Bs, acc);
    int tid = threadIdx.x;
    int lane = tid & 63, w = tid >> 6;
    int wr = w >> 1, wc = w & 1, g = lane >> 4, c0 = lane & 15;
    unsigned short* tile = Bs;          // safe: K-loop ended on a barrier
    int b_blk = bm0 >> 11;
    int nbase = bm0 & 2047;             // batch-folded sequence base
    if (isq) {
        #pragma unroll
        for (int m = 0; m < 2; ++m)
            #pragma unroll
            for (int r = 0; r < 4; ++r) {
                int rowl = wr * 32 + m * 16 + 4 * g + r;
                int npos = nbase + rowl;
                const float* csr = cs + npos * 64;
                float a0 = acc[m][0][r] * QSCALE;
                float a1 = acc[m][1][r] * QSCALE;
                float q0 = a0 * csr[c0] - a1 * csr[16 + c0];
                float q1 = a1 * csr[32 + c0] + a0 * csr[48 + c0];
                unsigned short* trow = tile + rowl * 128 + wc * 64;
                trow[c0]      = f2bf(q0);
                trow[16 + c0] = f2bf(q1);
                trow[32 + c0] = f2bf(acc[m][2][r] * QSCALE);
                trow[48 + c0] = f2bf(acc[m][3][r] * QSCALE);
            }
        __syncthreads();
        #pragma unroll
        for (int i = 0; i < 4; ++i) {
            int L = i * 256 + tid;
            int rr = L >> 4, hh = (L >> 3) & 1, ch = L & 7;
            int npos = nbase + rr;
            s8 v = *(const s8*)(tile + rr * 128 + hh * 64 + ch * 8);
            *(s8*)(q_h + ((size_t)(b_blk * HEADS + 2 * bx + hh) * NSEQ + npos) * DHEAD + ch * 8) = v;
        }
    } else if (bx < 16) {
        #pragma unroll
        for (int m = 0; m < 2; ++m)
            #pragma unroll
            for (int r = 0; r < 4; ++r) {
                int rowl = wr * 32 + m * 16 + 4 * g + r;
                int npos = nbase + rowl;
                const float* csr = cs + npos * 64;
                float a0 = acc[m][0][r], a1 = acc[m][1][r];
                float k0v = a0 * csr[c0] - a1 * csr[16 + c0];
                float k1v = a1 * csr[32 + c0] + a0 * csr[48 + c0];
                unsigned short* trow = tile + rowl * 128 + wc * 64;
                trow[c0]      = f2bf(k0v);
                trow[16 + c0] = f2bf(k1v);
                trow[32 + c0] = f2bf(acc[m][2][r]);
                trow[48 + c0] = f2bf(acc[m][3][r]);
            }
        __syncthreads();
        #pragma unroll
        for (int i = 0; i < 4; ++i) {
            int L = i * 256 + tid;
            int rr = L >> 4, hh = (L >> 3) & 1, ch = L & 7;
            int npos = nbase + rr;
            s8 v = *(const s8*)(tile + rr * 128 + hh * 64 + ch * 8);
            *(s8*)(k_h + ((size_t)(b_blk * HEADS + 2 * (bx - 8) + hh) * NSEQ + npos) * DHEAD + ch * 8) = v;
        }
    } else {
        // V: tile[col][row] with stride 72 shorts (144B: 16B-aligned, bank-spread)
        #pragma unroll
        for (int m = 0; m < 2; ++m) {
            int r0 = wr * 32 + m * 16 + 4 * g;
            #pragma unroll
            for (int n = 0; n < 4; ++n) {
                int col = wc * 64 + n * 16 + c0;
                uint2 pk;
                pk.x = cvt_pk_bf16(acc[m][n][0], acc[m][n][1]);
                pk.y = cvt_pk_bf16(acc[m][n][2], acc[m][n][3]);
                *(uint2*)(tile + col * 72 + r0) = pk;
            }
        }
        __syncthreads();
        #pragma unroll
        for (int i = 0; i < 4; ++i) {
            int L = i * 256 + tid;          // 1024 chunks: 128 cols x 8
            int col = L >> 3, ch = L & 7;
            int h = 2 * (bx - 16) + (col >> 6);
            int d = col & 63;
            s8 v = *(const s8*)(tile + col * 72 + ch * 8);
            *(s8*)(v_t + ((size_t)(b_blk * HEADS + h) * DHEAD + d) * NSEQ + nbase + ch * 8) = v;
        }
    }
}

// ---------------- causal flash attention: block-shared double-buffered K/V ----
// p_lds: per-wave 16 rows x 64 shorts, chunk-XOR swizzle (chunk ^= row&7 on 16B
// chunks; same involution on write+read). Total LDS 40960 B.

static __device__ __forceinline__ void stage_kv64(
        const unsigned short* __restrict__ kb, const unsigned short* __restrict__ vb,
        int j0, unsigned short* Kd, unsigned short* Vd, int w, int lane) {
    int r8 = lane >> 3, c = lane & 7;
    int sc = c ^ r8;                  // inverse swizzle: row&7 == r8 here
    #pragma unroll
    for (int i = 0; i < 2; ++i) {
        int rb = (w * 2 + i) * 8;     // wave-uniform row base
        int r = rb + r8;
        gload_lds16(kb + (size_t)(j0 + r) * DHEAD + sc * 8, Kd + rb * DHEAD);
        gload_lds16(vb + (size_t)r * NSEQ + j0 + sc * 8,    Vd + rb * DHEAD);
    }
}

template<bool MASKT>
static __device__ __forceinline__ void attn_tile_lds(
        int j0, int q0, int g, int c0, int njt,
        const unsigned short* Kc, const unsigned short* Vc,
        s8 qf0, s8 qf1, unsigned short* plw,
        f4 o[4], float& m, f4& ol) {
    int sw = c0 & 7;
    int off0 = ((g ^ sw) << 3);
    int off1 = (((g + 4) ^ sw) << 3);
    f4 s[4];
    #pragma unroll
    for (int jt = 0; jt < 4; ++jt) {
        f4 acc; acc = 0.f;
        if (!MASKT || jt < njt) {
            const unsigned short* kp = Kc + (jt * 16 + c0) * DHEAD;
            s8 kf0 = *(const s8*)(kp + off0);
            s8 kf1 = *(const s8*)(kp + off1);
            acc = __builtin_amdgcn_mfma_f32_16x16x32_bf16(kf0, qf0, acc, 0, 0, 0);
            acc = __builtin_amdgcn_mfma_f32_16x16x32_bf16(kf1, qf1, acc, 0, 0, 0);
        }
        s[jt] = acc;
    }
    if (MASKT) {
        #pragma unroll
        for (int jt = 0; jt < 4; ++jt)
            #pragma unroll
            for (int r = 0; r < 4; ++r) {
                int j = j0 + jt * 16 + 4 * g + r;
                if (j > q0 + c0) s[jt][r] = -1e30f;
            }
    }
    f4 mv;
    #pragma unroll
    for (int r = 0; r < 4; ++r)
        mv[r] = fmaxf(fmaxf(s[0][r], s[1][r]), fmaxf(s[2][r], s[3][r]));
    float mx = fmaxf(fmaxf(mv[0], mv[1]), fmaxf(mv[2], mv[3]));
    mx = fmaxf(mx, __shfl_xor(mx, 16));
    mx = fmaxf(mx, __shfl_xor(mx, 32));
    // deferred rescale, THR = 8*log2e ~= 11.5 (p bounded by ~e^8)
    if (__any(mx > m + 11.5f)) {
        float mnew = fmaxf(m, mx);
        float alpha = exp2f(m - mnew);
        #pragma unroll
        for (int dc = 0; dc < 4; ++dc)
            #pragma unroll
            for (int r = 0; r < 4; ++r) o[dc][r] *= alpha;
        #pragma unroll
        for (int r = 0; r < 4; ++r) ol[r] *= alpha;
        m = mnew;
    }
    // p = exp2(s - m) [libm], pack bf16, store to swizzled p_lds row c0:
    // logical shorts jt*16+4g (8B) = chunk 2jt+(g>>1), off (g&1)*4 shorts
    #pragma unroll
    for (int jt = 0; jt < 4; ++jt) {
        f4 p;
        #pragma unroll
        for (int r = 0; r < 4; ++r) p[r] = exp2f(s[jt][r] - m);
        uint2 pk;
        pk.x = cvt_pk_bf16(p[0], p[1]);
        pk.y = cvt_pk_bf16(p[2], p[3]);
        int swc = (2 * jt + (g >> 1)) ^ sw;
        *(uint2*)(plw + c0 * 64 + swc * 8 + (g & 1) * 4) = pk;
    }
    // wave-synchronous fence for the cross-lane LDS transpose
    __builtin_amdgcn_sched_barrier(0);
    asm volatile("s_waitcnt lgkmcnt(0)" ::: "memory");
    __builtin_amdgcn_sched_barrier(0);
    // reads: pf0 = logical chunk g, pf1 = logical chunk 4+g (swizzled)
    s8 pf0 = *(const s8*)(plw + c0 * 64 + ((g ^ sw) << 3));
    s8 pf1 = *(const s8*)(plw + c0 * 64 + (((4 + g) ^ sw) << 3));
    bool hi_half = (!MASKT) || (njt > 2);
    // l accumulation on the MFMA pipe: ol += 1-row * P^T
    const s8 onesf = {(short)0x3F80, (short)0x3F80, (short)0x3F80, (short)0x3F80,
                      (short)0x3F80, (short)0x3F80, (short)0x3F80, (short)0x3F80};
    ol = __builtin_amdgcn_mfma_f32_16x16x32_bf16(onesf, pf0, ol, 0, 0, 0);
    if (hi_half)
        ol = __builtin_amdgcn_mfma_f32_16x16x32_bf16(onesf, pf1, ol, 0, 0, 0);
    #pragma unroll
    for (int dc = 0; dc < 4; ++dc) {
        const unsigned short* vp = Vc + (dc * 16 + c0) * DHEAD;
        s8 vf0 = *(const s8*)(vp + off0);
        o[dc] = __builtin_amdgcn_mfma_f32_16x16x32_bf16(vf0, pf0, o[dc], 0, 0, 0);
        if (hi_half) {
            s8 vf1 = *(const s8*)(vp + off1);
            o[dc] = __builtin_amdgcn_mfma_f32_16x16x32_bf16(vf1, pf1, o[dc], 0, 0, 0);
        }
    }
}

// grid 1024 (1D), block 256. Strict longest-first, XCD-owned bh:
//   xcd = bid&7; k = bid>>3 (0..127); qt = 31-(k>>2) [descending]; bh = xcd + 8*(k&3)
__global__ __launch_bounds__(256) void attn_kernel(
        const unsigned short* __restrict__ q_h, const unsigned short* __restrict__ k_h,
        const unsigned short* __restrict__ v_t, unsigned short* __restrict__ attn_out) {
    __shared__ unsigned short Ks[2][64 * DHEAD];
    __shared__ unsigned short Vs[2][64 * DHEAD];
    __shared__ unsigned short p_lds[4][16][64];   // swizzled; 8 KB total
    int tid = threadIdx.x, lane = tid & 63, w = tid >> 6;
    int g = lane >> 4, c0 = lane & 15;
    int bid = blockIdx.x;
    int k = bid >> 3;
    int qt = 31 - (k >> 2);
    int bh = (bid & 7) + ((k & 3) << 3);
    const unsigned short* qb = q_h + (size_t)bh * NSEQ * DHEAD;
    const unsigned short* kb = k_h + (size_t)bh * NSEQ * DHEAD;
    const unsigned short* vb = v_t + (size_t)bh * DHEAD * NSEQ;
    unsigned short* plw = &p_lds[w][0][0];
    int b = bh >> 4, h = bh & 15;
    int q0 = qt * 64 + w * 16;
    s8 qf0 = *(const s8*)(qb + (size_t)(q0 + c0) * DHEAD + 8 * g);
    s8 qf1 = *(const s8*)(qb + (size_t)(q0 + c0) * DHEAD + 32 + 8 * g);
    f4 o[4]; o[0] = 0.f; o[1] = 0.f; o[2] = 0.f; o[3] = 0.f;
    f4 ol; ol = 0.f;
    float m = -1e30f;
    int nt = qt + 1;
    stage_kv64(kb, vb, 0, Ks[0], Vs[0], w, lane);
    __syncthreads();
    for (int t = 0; t < nt; ++t) {
        const unsigned short* Kc = Ks[t & 1];
        const unsigned short* Vc = Vs[t & 1];
        if (t + 1 < nt)
            stage_kv64(kb, vb, (t + 1) * 64, Ks[(t + 1) & 1], Vs[(t + 1) & 1], w, lane);
        if (t == nt - 1)
            attn_tile_lds<true>(t * 64, q0, g, c0, w + 1, Kc, Vc, qf0, qf1, plw, o, m, ol);
        else
            attn_tile_lds<false>(t * 64, q0, g, c0, 4, Kc, Vc, qf0, qf1, plw, o, m, ol);
        __syncthreads();
    }
    float invl = 1.0f / ol[0];
    unsigned short* dst = attn_out + ((size_t)(b * NSEQ) + q0 + c0) * (HEADS * DHEAD) + h * DHEAD;
    #pragma unroll
    for (int dc = 0; dc < 4; ++dc) {
        uint2 pk;
        pk.x = cvt_pk_bf16(o[dc][0] * invl, o[dc][1] * invl);
        pk.y = cvt_pk_bf16(o[dc][2] * invl, o[dc][3] * invl);
        *(uint2*)(dst + dc * 16 + 4 * g) = pk;
    }
}

// ---------------- out = attn @ Wo + bo (fp32 out), 64x128 tile.
// 1D grid 512, XCD-chunked. LDS-staged epilogue -> full-line fp32 writes.
__global__ __launch_bounds__(256) void gemm_o(
        const unsigned short* __restrict__ attn, const unsigned short* __restrict__ WoT,
        const float* __restrict__ bo, float* __restrict__ out) {
    __shared__ unsigned short As[3 * 64 * 32];
    __shared__ unsigned short Bs[3 * 128 * 32];
    __shared__ float tileF[64 * 132];   // stride 132 f32 = 528B (16B-mult)
    f4 acc[2][4];
    #pragma unroll
    for (int m = 0; m < 2; ++m)
        #pragma unroll
        for (int n = 0; n < 4; ++n) acc[m][n] = 0.f;
    int bid = blockIdx.x;
    int xcd = bid & 7;
    int kk = bid >> 3;              // 0..63
    int bx = kk & 7;
    int by = xcd * 8 + (kk >> 3);   // 0..63
    int bm0 = by * 64, bn0 = bx * 128;
    gemm_core64_p3(attn, WoT, bm0, bn0, As, Bs, acc);
    int tid = threadIdx.x;
    int lane = tid & 63, w = tid >> 6;
    int wr = w >> 1, wc = w & 1, g = lane >> 4, c0 = lane & 15;
    #pragma unroll
    for (int m = 0; m < 2; ++m)
        #pragma unroll
        for (int r = 0; r < 4; ++r) {
            int rowl = wr * 32 + m * 16 + 4 * g + r;
            #pragma unroll
            for (int n = 0; n < 4; ++n) {
                int col_l = wc * 64 + n * 16 + c0;
                tileF[rowl * 132 + col_l] = acc[m][n][r] + bo[bn0 + col_l];
            }
        }
    __syncthreads();
    #pragma unroll
    for (int i = 0; i < 8; ++i) {
        int L = i * 256 + tid;          // 2048 chunks: 64 rows x 32
        int rr = L >> 5, ch = L & 31;
        f4 v = *(const f4*)(tileF + rr * 132 + ch * 4);
        *(f4*)(out + (size_t)(bm0 + rr) * DIM + bn0 + ch * 4) = v;
    }
}

extern "C" void kernel_launch(void* const* d_in, const int* in_sizes, int n_in,
                              void* d_out, int out_size, void* d_ws, size_t ws_size,
                              hipStream_t stream) {
    const float* x     = (const float*)d_in[0];
    const float* freqs = (const float*)d_in[1];
    const float* gamma = (const float*)d_in[2];
    const float* Wq    = (const float*)d_in[3];
    const float* Wkv   = (const float*)d_in[4];
    const float* Wo    = (const float*)d_in[5];
    const float* bo    = (const float*)d_in[6];
    float* out = (float*)d_out;

    char* ws = (char*)d_ws;
    unsigned short* xn   = (unsigned short*)(ws + 0);          //  8 MB: 4096x1024 bf16
    unsigned short* WqT  = (unsigned short*)(ws + 8388608);    //  2 MB
    unsigned short* WkvT = (unsigned short*)(ws + 10485760);   //  4 MB
    unsigned short* WoT  = (unsigned short*)(ws + 14680064);   //  2 MB
    unsigned short* q_h  = (unsigned short*)(ws + 16777216);   //  8 MB (b,h,n,d)
    unsigned short* k_h  = (unsigned short*)(ws + 25165824);   //  8 MB (b,h,n,d)
    unsigned short* v_t  = (unsigned short*)(ws + 33554432);   //  8 MB (b,h,d,n)
    float*          cs   = (float*)(ws + 41943040);            // 512 KB cos/sin table
    unsigned short* attn = xn;   // xn dead after gemm_qkv; attn_out aliases it

    prep_rms_kernel<<<8704, 256, 0, stream>>>(x, gamma, Wq, Wkv, Wo, freqs,
                                              xn, WqT, WkvT, WoT, cs);
    gemm_qkv<<<1536, 256, 0, stream>>>(xn, WqT, WkvT, cs, q_h, k_h, v_t);
    attn_kernel<<<1024, 256, 0, stream>>>(q_h, k_h, v_t, attn);
    gemm_o  <<<512, 256, 0, stream>>>(attn, WoT, bo, out);
}